// Round 9
// baseline (284.318 us; speedup 1.0000x reference)
//
#include <hip/hip_runtime.h>
#include <hip/hip_bf16.h>
#include <stdint.h>

#define IN_CH 128
#define NPB   448            // nodes per bucket
#define NBUCK 224            // NBUCK*NPB = 100352 >= N
#define CAP   8192           // edge capacity per bucket region (avg ~7150)
#define PART_EPB 2048        // edges per partition block (8KB LDS tile, 782 blocks)
#define SRC_BITS 17          // src < 131072
#define SRC_MASK ((1 << SRC_BITS) - 1)

typedef short v8s __attribute__((ext_vector_type(8)));
typedef float v4f __attribute__((ext_vector_type(4)));
typedef float v2f __attribute__((ext_vector_type(2)));
typedef ushort v4u __attribute__((ext_vector_type(4)));

__device__ __forceinline__ ushort f2b(float f) {
    return ((__hip_bfloat16_raw)__float2bfloat16(f)).x;
}
__device__ __forceinline__ float b2f(ushort u) {
    __hip_bfloat16_raw r; r.x = u;
    return __bfloat162float((__hip_bfloat16)r);
}

// uint4 of 8 packed bf16 -> four packed f32 pair-adds (v_pk_add_f32)
#define ACC4(r) {                                                            \
    a01 += (v2f){__uint_as_float((r).x << 16),                               \
                 __uint_as_float((r).x & 0xffff0000u)};                      \
    a23 += (v2f){__uint_as_float((r).y << 16),                               \
                 __uint_as_float((r).y & 0xffff0000u)};                      \
    a45 += (v2f){__uint_as_float((r).z << 16),                               \
                 __uint_as_float((r).z & 0xffff0000u)};                      \
    a67 += (v2f){__uint_as_float((r).w << 16),                               \
                 __uint_as_float((r).w & 0xffff0000u)}; }

// ------------- FUSED: radix partition (blocks 0..PB-1) +
//               layer-1 GEMM [Q1|P1] = x @ [Wl1;Wr1].T (blocks PB..)
// Fully independent roles (part: src/dst->ebuf; gemm: x,W->q1b/p1b); both
// ~782 blocks, so the overlap saves ~min(part,gemm1). LDS unioned: gemm
// needs 69.6KB, part 23KB. Part improvements: dst staged in LDS (kills 2nd
// global read pass); per-edge bucket id recorded in sbuck[] (1 LDS read)
// replacing the 8-step binary search (~50 ops/edge).
__global__ __launch_bounds__(256) void k_part_gemm1(
    const int* __restrict__ src, const int* __restrict__ dst,
    int* __restrict__ cursor, int* __restrict__ ebuf, int E, int PB,
    const float* __restrict__ Af,
    const float* __restrict__ WlF, const float* __restrict__ WrF,
    ushort* __restrict__ qb, ushort* __restrict__ pbb, int N) {
    __shared__ __align__(16) char smem[69632];
    int tid = threadIdx.x;

    if ((int)blockIdx.x < PB) {
        // ---------------- partition role ----------------
        int* sedge = (int*)smem;                          // 8KB
        int* sdst  = (int*)(smem + 8192);                 // 8KB
        int* h     = (int*)(smem + 16384);                // 224 ints
        int* lofs  = h + NBUCK;
        int* gbase = lofs + NBUCK;
        int* lcur  = gbase + NBUCK;
        int* ssc   = lcur + NBUCK;                        // 256 ints
        unsigned char* sbuck = (unsigned char*)(ssc + 256); // 2KB

        int eb0 = blockIdx.x * PART_EPB;
        int cnt = min(PART_EPB, E - eb0);

        if (tid < NBUCK) { h[tid] = 0; lcur[tid] = 0; }
        __syncthreads();
        for (int i = tid; i < cnt; i += 256) {
            int d = dst[eb0 + i];
            sdst[i] = d;
            atomicAdd(&h[d / NPB], 1);
        }
        __syncthreads();
        int v = (tid < NBUCK) ? h[tid] : 0;
        ssc[tid] = v;
        __syncthreads();
        for (int off = 1; off < 256; off <<= 1) {
            int val = (tid >= off) ? ssc[tid - off] : 0;
            __syncthreads();
            ssc[tid] += val;
            __syncthreads();
        }
        int excl = ssc[tid] - v;
        if (tid < NBUCK) {
            lofs[tid] = excl;
            gbase[tid] = tid * CAP + atomicAdd(&cursor[tid], v);
        }
        __syncthreads();
        for (int i = tid; i < cnt; i += 256) {
            int s0 = src[eb0 + i];
            int d0 = sdst[i];
            int b = d0 / NPB;
            int dl = d0 - b * NPB;
            int p = atomicAdd(&lcur[b], 1);
            int slot = lofs[b] + p;
            sedge[slot] = (dl << SRC_BITS) | s0;
            sbuck[slot] = (unsigned char)b;
        }
        __syncthreads();
        for (int i = tid; i < cnt; i += 256) {
            int b = sbuck[i];
            int pos = gbase[b] + (i - lofs[b]);
            if (pos < (b + 1) * CAP) ebuf[pos] = sedge[i];  // overflow guard
        }
        return;
    }

    // ---------------- gemm role ----------------
    const int OC = 256;
    const int NT = OC / 16;
    const int LDW = 128 + 8;
    ushort* Wlds = (ushort*)smem;                         // 69.6KB

    int gb = blockIdx.x - PB;
    if (gb == 0 && tid < 16) {              // zero sentinel row N of q1b
        v8s z = {0, 0, 0, 0, 0, 0, 0, 0};
        *(v8s*)(qb + (size_t)N * 128 + tid * 8) = z;
    }

    // stage + cast W: OC rows x 128 k, 8 floats per thread-chunk
    for (int it = 0; it < OC / 16; it++) {
        int idx = it * 256 + tid;
        int r = idx >> 4, kc = (idx & 15) * 8;
        const float* Wrow = (r < OC / 2) ? (WlF + (size_t)r * 128)
                                         : (WrF + (size_t)(r - OC / 2) * 128);
        float4 w0 = *(const float4*)(Wrow + kc);
        float4 w1 = *(const float4*)(Wrow + kc + 4);
        v8s wv;
        wv[0] = (short)f2b(w0.x); wv[1] = (short)f2b(w0.y);
        wv[2] = (short)f2b(w0.z); wv[3] = (short)f2b(w0.w);
        wv[4] = (short)f2b(w1.x); wv[5] = (short)f2b(w1.y);
        wv[6] = (short)f2b(w1.z); wv[7] = (short)f2b(w1.w);
        *(v8s*)((short*)Wlds + r * LDW + kc) = wv;
    }
    __syncthreads();

    int wave = tid >> 6;
    int lane = tid & 63;
    int m16 = lane & 15;
    int quad = lane >> 4;
    int rowbase = gb * 128 + wave * 32;

    v4f acc[2][NT];
#pragma unroll
    for (int mt = 0; mt < 2; mt++)
#pragma unroll
        for (int t = 0; t < NT; t++) acc[mt][t] = {0.f, 0.f, 0.f, 0.f};

    int ar0 = min(rowbase + m16, N - 1);
    int ar1 = min(rowbase + 16 + m16, N - 1);

#pragma unroll
    for (int ks = 0; ks < 4; ks++) {
        int k0 = ks * 32 + quad * 8;
        float4 f00 = *(const float4*)(Af + (size_t)ar0 * 128 + k0);
        float4 f01 = *(const float4*)(Af + (size_t)ar0 * 128 + k0 + 4);
        float4 f10 = *(const float4*)(Af + (size_t)ar1 * 128 + k0);
        float4 f11 = *(const float4*)(Af + (size_t)ar1 * 128 + k0 + 4);
        v8s a0, a1;
        a0[0] = (short)f2b(f00.x); a0[1] = (short)f2b(f00.y);
        a0[2] = (short)f2b(f00.z); a0[3] = (short)f2b(f00.w);
        a0[4] = (short)f2b(f01.x); a0[5] = (short)f2b(f01.y);
        a0[6] = (short)f2b(f01.z); a0[7] = (short)f2b(f01.w);
        a1[0] = (short)f2b(f10.x); a1[1] = (short)f2b(f10.y);
        a1[2] = (short)f2b(f10.z); a1[3] = (short)f2b(f10.w);
        a1[4] = (short)f2b(f11.x); a1[5] = (short)f2b(f11.y);
        a1[6] = (short)f2b(f11.z); a1[7] = (short)f2b(f11.w);
#pragma unroll
        for (int t = 0; t < NT; t++) {
            v8s b = *(const v8s*)((const short*)Wlds + (t * 16 + m16) * LDW + k0);
            acc[0][t] = __builtin_amdgcn_mfma_f32_16x16x32_bf16(a0, b, acc[0][t], 0, 0, 0);
            acc[1][t] = __builtin_amdgcn_mfma_f32_16x16x32_bf16(a1, b, acc[1][t], 0, 0, 0);
        }
    }

    // C/D layout: col = t*16 + m16, row(within tile) = quad*4 + r
#pragma unroll
    for (int mt = 0; mt < 2; mt++) {
        int orow0 = rowbase + mt * 16 + quad * 4;
#pragma unroll
        for (int r = 0; r < 4; r++) {
            int orow = orow0 + r;
            if (orow < N) {
#pragma unroll
                for (int t = 0; t < NT; t++) {
                    int c = t * 16 + m16;
                    float v = acc[mt][t][r];
                    if (c < 128) qb[(size_t)orow * 128 + c] = f2b(v);
                    else pbb[(size_t)orow * 128 + (c - 128)] = f2b(v);
                }
            }
        }
    }
}

// ---------------------- per-bucket CSR build: hist -> scan -> scatter, L2-local
// rowdeg[node] = {row_ptr, deg} packed (one 8B load in the agg kernels)
__global__ __launch_bounds__(256) void k_bbuild(
    const int* __restrict__ ebuf, const int* __restrict__ cursor,
    int2* __restrict__ rowdeg, int* __restrict__ col, int N) {
    __shared__ int sdeg[NPB];
    __shared__ int scur[NPB];
    __shared__ int ssum[256];
    int b = blockIdx.x, tid = threadIdx.x;
    int base = b * NPB;
    int nodes = min(NPB, N - base);
    int e0 = b * CAP;
    int e1 = e0 + min(cursor[b], CAP);

    for (int i = tid; i < NPB; i += 256) sdeg[i] = 0;
    __syncthreads();
    for (int e = e0 + tid; e < e1; e += 256)
        atomicAdd(&sdeg[((unsigned)ebuf[e]) >> SRC_BITS], 1);
    __syncthreads();
    int d0 = 0, d1 = 0;
    if (tid < 224) { d0 = sdeg[2 * tid]; d1 = sdeg[2 * tid + 1]; }
    int ts = d0 + d1;
    ssum[tid] = ts;
    __syncthreads();
    for (int off = 1; off < 256; off <<= 1) {
        int val = (tid >= off) ? ssum[tid - off] : 0;
        __syncthreads();
        ssum[tid] += val;
        __syncthreads();
    }
    int excl = ssum[tid] - ts;
    if (tid < 224) {
        scur[2 * tid] = excl;
        scur[2 * tid + 1] = excl + d0;
        if (2 * tid < nodes)
            rowdeg[base + 2 * tid] = make_int2(e0 + excl, d0);
        if (2 * tid + 1 < nodes)
            rowdeg[base + 2 * tid + 1] = make_int2(e0 + excl + d0, d1);
    }
    __syncthreads();
    for (int e = e0 + tid; e < e1; e += 256) {
        int w = ebuf[e];
        int dl = ((unsigned)w) >> SRC_BITS;
        int p = atomicAdd(&scur[dl], 1);
        col[e0 + p] = w & SRC_MASK;
    }
}

// ------------------------------------------------- layer-2 GEMM, W in LDS
// A = hb bf16 [N][128], OC=128: c<64 -> q2[N][64] bf16, c>=64 -> p2[N][64] f32
// First block zeroes the q2 sentinel row (replaces a memset dispatch).
__global__ __launch_bounds__(256) void k_wgemm2(
    const ushort* __restrict__ Ab,
    const float* __restrict__ WlF, const float* __restrict__ WrF,
    ushort* __restrict__ qb, float* __restrict__ pbf, int N) {
    const int OC = 128;
    const int NT = OC / 16;
    const int LDW = 128 + 8;
    __shared__ ushort Wlds[OC * LDW];

    int tid = threadIdx.x;
    if (blockIdx.x == 0 && tid < 8) {       // zero sentinel row N of q2
        v8s z = {0, 0, 0, 0, 0, 0, 0, 0};
        *(v8s*)(qb + (size_t)N * 64 + tid * 8) = z;
    }
    // stage + cast W
    for (int it = 0; it < OC / 16; it++) {
        int idx = it * 256 + tid;
        int r = idx >> 4, kc = (idx & 15) * 8;
        const float* Wrow = (r < OC / 2) ? (WlF + (size_t)r * 128)
                                         : (WrF + (size_t)(r - OC / 2) * 128);
        float4 w0 = *(const float4*)(Wrow + kc);
        float4 w1 = *(const float4*)(Wrow + kc + 4);
        v8s wv;
        wv[0] = (short)f2b(w0.x); wv[1] = (short)f2b(w0.y);
        wv[2] = (short)f2b(w0.z); wv[3] = (short)f2b(w0.w);
        wv[4] = (short)f2b(w1.x); wv[5] = (short)f2b(w1.y);
        wv[6] = (short)f2b(w1.z); wv[7] = (short)f2b(w1.w);
        *(v8s*)((short*)Wlds + r * LDW + kc) = wv;
    }
    __syncthreads();

    int wave = tid >> 6;
    int lane = tid & 63;
    int m16 = lane & 15;
    int quad = lane >> 4;
    int rowbase = blockIdx.x * 128 + wave * 32;

    v4f acc[2][NT];
#pragma unroll
    for (int mt = 0; mt < 2; mt++)
#pragma unroll
        for (int t = 0; t < NT; t++) acc[mt][t] = {0.f, 0.f, 0.f, 0.f};

    int ar0 = min(rowbase + m16, N - 1);
    int ar1 = min(rowbase + 16 + m16, N - 1);

#pragma unroll
    for (int ks = 0; ks < 4; ks++) {
        int k0 = ks * 32 + quad * 8;
        v8s a0 = *(const v8s*)((const short*)Ab + (size_t)ar0 * 128 + k0);
        v8s a1 = *(const v8s*)((const short*)Ab + (size_t)ar1 * 128 + k0);
#pragma unroll
        for (int t = 0; t < NT; t++) {
            v8s b = *(const v8s*)((const short*)Wlds + (t * 16 + m16) * LDW + k0);
            acc[0][t] = __builtin_amdgcn_mfma_f32_16x16x32_bf16(a0, b, acc[0][t], 0, 0, 0);
            acc[1][t] = __builtin_amdgcn_mfma_f32_16x16x32_bf16(a1, b, acc[1][t], 0, 0, 0);
        }
    }

#pragma unroll
    for (int mt = 0; mt < 2; mt++) {
        int orow0 = rowbase + mt * 16 + quad * 4;
#pragma unroll
        for (int r = 0; r < 4; r++) {
            int orow = orow0 + r;
            if (orow < N) {
#pragma unroll
                for (int t = 0; t < NT; t++) {
                    int c = t * 16 + m16;
                    float v = acc[mt][t][r];
                    if (c < 64) qb[(size_t)orow * 64 + c] = f2b(v);
                    else pbf[(size_t)orow * 64 + (c - 64)] = v;
                }
            }
        }
    }
}

// ------------------- layer-1 aggregation: h = ReLU(mean(Q1) + P1 + b1) -> bf16
// r6-proven body; only change: 32-bit row addressing ((uint)c*128u+ch, single
// v_lshl_add vs 64-bit chain). Col loads UNCONDITIONAL (clamped index),
// select AFTER the load (r7 lesson: select around a load serializes it).
__global__ __launch_bounds__(256, 8) void k_agg1(
    const int2* __restrict__ rowdeg,
    const int* __restrict__ col, const ushort* __restrict__ q1b,
    const ushort* __restrict__ p1b, const float* __restrict__ bias,
    ushort* __restrict__ hb, int N) {
    int node = blockIdx.x * (blockDim.x >> 6) + (threadIdx.x >> 6);
    int lane = threadIdx.x & 63;
    if (node >= N) return;
    int2 rd = rowdeg[node];
    int s0 = rd.x, dn = rd.y;
    int s1 = s0 + dn;
    int g = lane >> 4;                      // 4 groups of 16 lanes
    int ch = 8 * (lane & 15);               // 8 channels per lane, 16B loads
    // hoist epilogue row load: independent of gather, latency overlaps it
    v4u pb = *(const v4u*)((const ushort*)p1b + (size_t)node * 128 + ch);
    v4u pb2 = *(const v4u*)((const ushort*)p1b + (size_t)node * 128 + ch + 4);
    int last = (dn > 0) ? (s1 - 1) : s0;    // valid clamp target
    v2f a01 = {0.f, 0.f}, a23 = {0.f, 0.f}, a45 = {0.f, 0.f}, a67 = {0.f, 0.f};
    int j = s0;
    do {
        int i0 = j + g,      i1 = j + 4 + g,  i2 = j + 8 + g,  i3 = j + 12 + g;
        int i4 = j + 16 + g, i5 = j + 20 + g, i6 = j + 24 + g, i7 = j + 28 + g;
        int t0 = col[min(i0, last)];
        int t1 = col[min(i1, last)];
        int t2 = col[min(i2, last)];
        int t3 = col[min(i3, last)];
        int t4 = col[min(i4, last)];
        int t5 = col[min(i5, last)];
        int t6 = col[min(i6, last)];
        int t7 = col[min(i7, last)];
        int c0 = (i0 < s1) ? t0 : N;
        int c1 = (i1 < s1) ? t1 : N;
        int c2 = (i2 < s1) ? t2 : N;
        int c3 = (i3 < s1) ? t3 : N;
        int c4 = (i4 < s1) ? t4 : N;
        int c5 = (i5 < s1) ? t5 : N;
        int c6 = (i6 < s1) ? t6 : N;
        int c7 = (i7 < s1) ? t7 : N;
        uint4 r0 = *(const uint4*)(q1b + ((uint)c0 * 128u + (uint)ch));
        uint4 r1 = *(const uint4*)(q1b + ((uint)c1 * 128u + (uint)ch));
        uint4 r2 = *(const uint4*)(q1b + ((uint)c2 * 128u + (uint)ch));
        uint4 r3 = *(const uint4*)(q1b + ((uint)c3 * 128u + (uint)ch));
        uint4 r4 = *(const uint4*)(q1b + ((uint)c4 * 128u + (uint)ch));
        uint4 r5 = *(const uint4*)(q1b + ((uint)c5 * 128u + (uint)ch));
        uint4 r6 = *(const uint4*)(q1b + ((uint)c6 * 128u + (uint)ch));
        uint4 r7 = *(const uint4*)(q1b + ((uint)c7 * 128u + (uint)ch));
        ACC4(r0); ACC4(r1); ACC4(r2); ACC4(r3);
        ACC4(r4); ACC4(r5); ACC4(r6); ACC4(r7);
        j += 32;
    } while (j < s1);                       // deg>32: ~1e-4 of nodes
    float s[8] = {a01.x, a01.y, a23.x, a23.y, a45.x, a45.y, a67.x, a67.y};
#pragma unroll
    for (int k = 0; k < 8; k++) {
        s[k] += __shfl_xor(s[k], 16);
        s[k] += __shfl_xor(s[k], 32);
    }
    if (g == 0) {
        float inv = (dn > 0) ? 1.0f / (float)dn : 0.0f;
        float4 bi0 = *(const float4*)(bias + ch);
        float4 bi1 = *(const float4*)(bias + ch + 4);
        v8s o;
        o[0] = (short)f2b(fmaxf(s[0] * inv + b2f(pb.x) + bi0.x, 0.f));
        o[1] = (short)f2b(fmaxf(s[1] * inv + b2f(pb.y) + bi0.y, 0.f));
        o[2] = (short)f2b(fmaxf(s[2] * inv + b2f(pb.z) + bi0.z, 0.f));
        o[3] = (short)f2b(fmaxf(s[3] * inv + b2f(pb.w) + bi0.w, 0.f));
        o[4] = (short)f2b(fmaxf(s[4] * inv + b2f(pb2.x) + bi1.x, 0.f));
        o[5] = (short)f2b(fmaxf(s[5] * inv + b2f(pb2.y) + bi1.y, 0.f));
        o[6] = (short)f2b(fmaxf(s[6] * inv + b2f(pb2.z) + bi1.z, 0.f));
        o[7] = (short)f2b(fmaxf(s[7] * inv + b2f(pb2.w) + bi1.w, 0.f));
        *(v8s*)(hb + (size_t)node * 128 + ch) = o;
    }
}

// ------------------- layer-2 aggregation: out = mean(Q2) + P2 + b2 -> fp32
// r6-proven body; only change: 32-bit row addressing ((uint)c*64u+ch).
__global__ __launch_bounds__(256, 8) void k_agg2(
    const int2* __restrict__ rowdeg,
    const int* __restrict__ col, const ushort* __restrict__ q2,
    const float* __restrict__ p2, const float* __restrict__ bias,
    float* __restrict__ out, int N) {
    int node = blockIdx.x * (blockDim.x >> 6) + (threadIdx.x >> 6);
    int lane = threadIdx.x & 63;
    if (node >= N) return;
    int2 rd = rowdeg[node];
    int s0 = rd.x, dn = rd.y;
    int s1 = s0 + dn;
    int g = lane >> 3;                      // 8 groups of 8 lanes
    int ch = 8 * (lane & 7);                // 8 channels per lane, 16B loads
    // hoist epilogue loads (independent of gather)
    v4f p0 = *(const v4f*)(p2 + (size_t)node * 64 + ch);
    v4f p1 = *(const v4f*)(p2 + (size_t)node * 64 + ch + 4);
    int last = (dn > 0) ? (s1 - 1) : s0;
    v2f a01 = {0.f, 0.f}, a23 = {0.f, 0.f}, a45 = {0.f, 0.f}, a67 = {0.f, 0.f};
    int j = s0;
    do {
        int i0 = j + g, i1 = j + 8 + g, i2 = j + 16 + g, i3 = j + 24 + g;
        int t0 = col[min(i0, last)];
        int t1 = col[min(i1, last)];
        int t2 = col[min(i2, last)];
        int t3 = col[min(i3, last)];
        int c0 = (i0 < s1) ? t0 : N;
        int c1 = (i1 < s1) ? t1 : N;
        int c2 = (i2 < s1) ? t2 : N;
        int c3 = (i3 < s1) ? t3 : N;
        uint4 r0 = *(const uint4*)(q2 + ((uint)c0 * 64u + (uint)ch));
        uint4 r1 = *(const uint4*)(q2 + ((uint)c1 * 64u + (uint)ch));
        uint4 r2 = *(const uint4*)(q2 + ((uint)c2 * 64u + (uint)ch));
        uint4 r3 = *(const uint4*)(q2 + ((uint)c3 * 64u + (uint)ch));
        ACC4(r0); ACC4(r1); ACC4(r2); ACC4(r3);
        j += 32;
    } while (j < s1);
    float s[8] = {a01.x, a01.y, a23.x, a23.y, a45.x, a45.y, a67.x, a67.y};
#pragma unroll
    for (int k = 0; k < 8; k++) {
        s[k] += __shfl_xor(s[k], 8);
        s[k] += __shfl_xor(s[k], 16);
        s[k] += __shfl_xor(s[k], 32);
    }
    if (g == 0) {
        float inv = (dn > 0) ? 1.0f / (float)dn : 0.0f;
        float4 bi0 = *(const float4*)(bias + ch);
        float4 bi1 = *(const float4*)(bias + ch + 4);
        v4f o0, o1;
        o0[0] = s[0] * inv + p0[0] + bi0.x;
        o0[1] = s[1] * inv + p0[1] + bi0.y;
        o0[2] = s[2] * inv + p0[2] + bi0.z;
        o0[3] = s[3] * inv + p0[3] + bi0.w;
        o1[0] = s[4] * inv + p1[0] + bi1.x;
        o1[1] = s[5] * inv + p1[1] + bi1.y;
        o1[2] = s[6] * inv + p1[2] + bi1.z;
        o1[3] = s[7] * inv + p1[3] + bi1.w;
        *(v4f*)(out + (size_t)node * 64 + ch) = o0;
        *(v4f*)(out + (size_t)node * 64 + ch + 4) = o1;
    }
}

extern "C" void kernel_launch(void* const* d_in, const int* in_sizes, int n_in,
                              void* d_out, int out_size, void* d_ws, size_t ws_size,
                              hipStream_t stream) {
    const float* x   = (const float*)d_in[0];
    const int* ei    = (const int*)d_in[1];
    const float* Wl1 = (const float*)d_in[2];
    const float* bl1 = (const float*)d_in[3];
    const float* Wr1 = (const float*)d_in[4];
    const float* Wl2 = (const float*)d_in[5];
    const float* bl2 = (const float*)d_in[6];
    const float* Wr2 = (const float*)d_in[7];

    const int N = in_sizes[0] / IN_CH;   // 100000
    const int E = in_sizes[1] / 2;       // 1600000
    const int* src = ei;
    const int* dst = ei + E;

    char* p = (char*)d_ws;
    auto carve = [&](size_t bytes) -> void* {
        void* q = (void*)p;
        p += (bytes + 255) & ~(size_t)255;
        return q;
    };
    int* cursor   = (int*)carve(NBUCK * 4);
    int* ebuf     = (int*)carve((size_t)NBUCK * CAP * 4);
    int* col      = (int*)carve((size_t)NBUCK * CAP * 4 + 256);
    int2* rowdeg  = (int2*)carve((size_t)N * 8);
    ushort* q1b   = (ushort*)carve(((size_t)N + 1) * 128 * 2);  // +1 zero row
    ushort* p1b   = (ushort*)carve((size_t)N * 128 * 2);
    ushort* hb    = (ushort*)carve((size_t)N * 128 * 2);
    ushort* q2    = (ushort*)carve(((size_t)N + 1) * 64 * 2);   // +1 zero row
    float* p2     = (float*)carve((size_t)N * 64 * 4);
    (void)ws_size; (void)n_in;

    float* out = (float*)d_out;
    (void)out_size;

    const int PB  = (E + PART_EPB - 1) / PART_EPB;   // 782 partition blocks
    const int GB  = (N + 127) / 128;                 // 782 gemm blocks

    // ---- fused {partition + layer-1 GEMM} (independent roles) ----
    (void)hipMemsetAsync(cursor, 0, NBUCK * 4, stream);
    k_part_gemm1<<<PB + GB, 256, 0, stream>>>(
        src, dst, cursor, ebuf, E, PB, x, Wl1, Wr1, q1b, p1b, N);

    // ---- CSR build ----
    k_bbuild<<<NBUCK, 256, 0, stream>>>(ebuf, cursor, rowdeg, col, N);

    // ---- h = ReLU(mean(Q1)+P1+b1) ----
    k_agg1<<<(N + 3) / 4, 256, 0, stream>>>(rowdeg, col, q1b, p1b, bl1, hb, N);

    // ---- layer 2: [Q2|P2] = hb @ [Wl2;Wr2].T; out = mean(Q2)+P2+b2 ----
    k_wgemm2<<<GB, 256, 0, stream>>>(hb, Wl2, Wr2, q2, p2, N);
    k_agg2<<<(N + 3) / 4, 256, 0, stream>>>(rowdeg, col, q2, p2, bl2, out, N);
}

// Round 10
// 279.241 us; speedup vs baseline: 1.0182x; 1.0182x over previous
//
#include <hip/hip_runtime.h>
#include <hip/hip_bf16.h>
#include <stdint.h>

#define IN_CH 128
#define NPB   448            // nodes per bucket
#define NBUCK 224            // NBUCK*NPB = 100352 >= N
#define CAP   8192           // edge capacity per bucket region (avg ~7150)
#define PART_EPB 2048        // edges per partition block (782 blocks)
#define SRC_BITS 17          // src < 131072
#define SRC_MASK ((1 << SRC_BITS) - 1)

typedef short v8s __attribute__((ext_vector_type(8)));
typedef float v4f __attribute__((ext_vector_type(4)));
typedef float v2f __attribute__((ext_vector_type(2)));
typedef ushort v4u __attribute__((ext_vector_type(4)));

__device__ __forceinline__ ushort f2b(float f) {
    return ((__hip_bfloat16_raw)__float2bfloat16(f)).x;
}
__device__ __forceinline__ float b2f(ushort u) {
    __hip_bfloat16_raw r; r.x = u;
    return __bfloat162float((__hip_bfloat16)r);
}

// uint4 of 8 packed bf16 -> four packed f32 pair-adds (v_pk_add_f32)
#define ACC4(r) {                                                            \
    a01 += (v2f){__uint_as_float((r).x << 16),                               \
                 __uint_as_float((r).x & 0xffff0000u)};                      \
    a23 += (v2f){__uint_as_float((r).y << 16),                               \
                 __uint_as_float((r).y & 0xffff0000u)};                      \
    a45 += (v2f){__uint_as_float((r).z << 16),                               \
                 __uint_as_float((r).z & 0xffff0000u)};                      \
    a67 += (v2f){__uint_as_float((r).w << 16),                               \
                 __uint_as_float((r).w & 0xffff0000u)}; }

// ---------------------------------- coalesced radix partition of edges by dst
// STANDALONE (r9 lesson: fusing with the 69.6KB-LDS gemm role cut occupancy
// to 8 waves/CU and serialized it). Improvements kept from r9: dst staged in
// LDS (no 2nd global read pass); per-edge bucket id in sbuck[] (1 LDS read)
// replacing the 8-step binary search. sbuck is INT (byte scatter = 4-lane
// bank-word serialization, 1.4M conflicts in r9). LDS 28.5KB -> 5 blocks/CU.
__global__ __launch_bounds__(256) void k_part(
    const int* __restrict__ src, const int* __restrict__ dst,
    int* __restrict__ cursor, int* __restrict__ ebuf, int E) {
    __shared__ int sedge[PART_EPB];                    // 8 KB
    __shared__ int sdst[PART_EPB];                     // 8 KB
    __shared__ int sbuck[PART_EPB];                    // 8 KB
    __shared__ int h[NBUCK], lofs[NBUCK], gbase[NBUCK], lcur[NBUCK];
    __shared__ int ssc[256];

    int tid = threadIdx.x;
    int eb0 = blockIdx.x * PART_EPB;
    int cnt = min(PART_EPB, E - eb0);

    if (tid < NBUCK) { h[tid] = 0; lcur[tid] = 0; }
    __syncthreads();
    for (int i = tid; i < cnt; i += 256) {
        int d = dst[eb0 + i];
        sdst[i] = d;
        atomicAdd(&h[d / NPB], 1);
    }
    __syncthreads();
    int v = (tid < NBUCK) ? h[tid] : 0;
    ssc[tid] = v;
    __syncthreads();
    for (int off = 1; off < 256; off <<= 1) {
        int val = (tid >= off) ? ssc[tid - off] : 0;
        __syncthreads();
        ssc[tid] += val;
        __syncthreads();
    }
    int excl = ssc[tid] - v;
    if (tid < NBUCK) {
        lofs[tid] = excl;
        gbase[tid] = tid * CAP + atomicAdd(&cursor[tid], v);
    }
    __syncthreads();
    for (int i = tid; i < cnt; i += 256) {
        int s0 = src[eb0 + i];
        int d0 = sdst[i];
        int b = d0 / NPB;
        int dl = d0 - b * NPB;
        int p = atomicAdd(&lcur[b], 1);
        int slot = lofs[b] + p;
        sedge[slot] = (dl << SRC_BITS) | s0;
        sbuck[slot] = b;
    }
    __syncthreads();
    for (int i = tid; i < cnt; i += 256) {
        int b = sbuck[i];
        int pos = gbase[b] + (i - lofs[b]);
        if (pos < (b + 1) * CAP) ebuf[pos] = sedge[i];  // overflow guard
    }
}

// ------------- FUSED: per-bucket CSR build (blocks 0..NBUCK-1)  +
//               layer-1 GEMM [Q1|P1] = x @ [Wl1;Wr1].T (blocks NBUCK..)
// r8-proven pairing: bbuild is small (224 blocks, light) so the gemm path's
// 69.6KB LDS costs it nothing; roles are independent. First gemm block also
// zeroes the q1b sentinel row (replaces a memset dispatch).
__global__ __launch_bounds__(256) void k_bbuild_gemm1(
    const int* __restrict__ ebuf, const int* __restrict__ cursor,
    int2* __restrict__ rowdeg, int* __restrict__ col,
    const float* __restrict__ Af,
    const float* __restrict__ WlF, const float* __restrict__ WrF,
    ushort* __restrict__ qb, ushort* __restrict__ pbb, int N) {
    const int OC = 256;
    const int NT = OC / 16;
    const int LDW = 128 + 8;
    __shared__ ushort Wlds[OC * LDW];                  // 69.6 KB (gemm role)
    __shared__ int sdeg[NPB];                          // bbuild role
    __shared__ int scur[NPB];
    __shared__ int ssum[256];

    int tid = threadIdx.x;

    if (blockIdx.x < NBUCK) {
        // ---------------- bbuild role ----------------
        int b = blockIdx.x;
        int base = b * NPB;
        int nodes = min(NPB, N - base);
        int e0 = b * CAP;
        int e1 = e0 + min(cursor[b], CAP);

        for (int i = tid; i < NPB; i += 256) sdeg[i] = 0;
        __syncthreads();
        for (int e = e0 + tid; e < e1; e += 256)
            atomicAdd(&sdeg[((unsigned)ebuf[e]) >> SRC_BITS], 1);
        __syncthreads();
        int d0 = 0, d1 = 0;
        if (tid < 224) { d0 = sdeg[2 * tid]; d1 = sdeg[2 * tid + 1]; }
        int ts = d0 + d1;
        ssum[tid] = ts;
        __syncthreads();
        for (int off = 1; off < 256; off <<= 1) {
            int val = (tid >= off) ? ssum[tid - off] : 0;
            __syncthreads();
            ssum[tid] += val;
            __syncthreads();
        }
        int excl = ssum[tid] - ts;
        if (tid < 224) {
            scur[2 * tid] = excl;
            scur[2 * tid + 1] = excl + d0;
            if (2 * tid < nodes)
                rowdeg[base + 2 * tid] = make_int2(e0 + excl, d0);
            if (2 * tid + 1 < nodes)
                rowdeg[base + 2 * tid + 1] = make_int2(e0 + excl + d0, d1);
        }
        __syncthreads();
        for (int e = e0 + tid; e < e1; e += 256) {
            int w = ebuf[e];
            int dl = ((unsigned)w) >> SRC_BITS;
            int p = atomicAdd(&scur[dl], 1);
            col[e0 + p] = w & SRC_MASK;
        }
        return;
    }

    // ---------------- gemm role ----------------
    int gb = blockIdx.x - NBUCK;
    if (gb == 0 && tid < 16) {              // zero sentinel row N of q1b
        v8s z = {0, 0, 0, 0, 0, 0, 0, 0};
        *(v8s*)(qb + (size_t)N * 128 + tid * 8) = z;
    }

    // stage + cast W: OC rows x 128 k, 8 floats per thread-chunk
    for (int it = 0; it < OC / 16; it++) {
        int idx = it * 256 + tid;
        int r = idx >> 4, kc = (idx & 15) * 8;
        const float* Wrow = (r < OC / 2) ? (WlF + (size_t)r * 128)
                                         : (WrF + (size_t)(r - OC / 2) * 128);
        float4 w0 = *(const float4*)(Wrow + kc);
        float4 w1 = *(const float4*)(Wrow + kc + 4);
        v8s wv;
        wv[0] = (short)f2b(w0.x); wv[1] = (short)f2b(w0.y);
        wv[2] = (short)f2b(w0.z); wv[3] = (short)f2b(w0.w);
        wv[4] = (short)f2b(w1.x); wv[5] = (short)f2b(w1.y);
        wv[6] = (short)f2b(w1.z); wv[7] = (short)f2b(w1.w);
        *(v8s*)((short*)Wlds + r * LDW + kc) = wv;
    }
    __syncthreads();

    int wave = tid >> 6;
    int lane = tid & 63;
    int m16 = lane & 15;
    int quad = lane >> 4;
    int rowbase = gb * 128 + wave * 32;

    v4f acc[2][NT];
#pragma unroll
    for (int mt = 0; mt < 2; mt++)
#pragma unroll
        for (int t = 0; t < NT; t++) acc[mt][t] = {0.f, 0.f, 0.f, 0.f};

    int ar0 = min(rowbase + m16, N - 1);
    int ar1 = min(rowbase + 16 + m16, N - 1);

#pragma unroll
    for (int ks = 0; ks < 4; ks++) {
        int k0 = ks * 32 + quad * 8;
        float4 f00 = *(const float4*)(Af + (size_t)ar0 * 128 + k0);
        float4 f01 = *(const float4*)(Af + (size_t)ar0 * 128 + k0 + 4);
        float4 f10 = *(const float4*)(Af + (size_t)ar1 * 128 + k0);
        float4 f11 = *(const float4*)(Af + (size_t)ar1 * 128 + k0 + 4);
        v8s a0, a1;
        a0[0] = (short)f2b(f00.x); a0[1] = (short)f2b(f00.y);
        a0[2] = (short)f2b(f00.z); a0[3] = (short)f2b(f00.w);
        a0[4] = (short)f2b(f01.x); a0[5] = (short)f2b(f01.y);
        a0[6] = (short)f2b(f01.z); a0[7] = (short)f2b(f01.w);
        a1[0] = (short)f2b(f10.x); a1[1] = (short)f2b(f10.y);
        a1[2] = (short)f2b(f10.z); a1[3] = (short)f2b(f10.w);
        a1[4] = (short)f2b(f11.x); a1[5] = (short)f2b(f11.y);
        a1[6] = (short)f2b(f11.z); a1[7] = (short)f2b(f11.w);
#pragma unroll
        for (int t = 0; t < NT; t++) {
            v8s b = *(const v8s*)((const short*)Wlds + (t * 16 + m16) * LDW + k0);
            acc[0][t] = __builtin_amdgcn_mfma_f32_16x16x32_bf16(a0, b, acc[0][t], 0, 0, 0);
            acc[1][t] = __builtin_amdgcn_mfma_f32_16x16x32_bf16(a1, b, acc[1][t], 0, 0, 0);
        }
    }

    // C/D layout: col = t*16 + m16, row(within tile) = quad*4 + r
#pragma unroll
    for (int mt = 0; mt < 2; mt++) {
        int orow0 = rowbase + mt * 16 + quad * 4;
#pragma unroll
        for (int r = 0; r < 4; r++) {
            int orow = orow0 + r;
            if (orow < N) {
#pragma unroll
                for (int t = 0; t < NT; t++) {
                    int c = t * 16 + m16;
                    float v = acc[mt][t][r];
                    if (c < 128) qb[(size_t)orow * 128 + c] = f2b(v);
                    else pbb[(size_t)orow * 128 + (c - 128)] = f2b(v);
                }
            }
        }
    }
}

// ------------------------------------------------- layer-2 GEMM, W in LDS
// A = hb bf16 [N][128], OC=128: c<64 -> q2[N][64] bf16, c>=64 -> p2[N][64] f32
// First block zeroes the q2 sentinel row (replaces a memset dispatch).
__global__ __launch_bounds__(256) void k_wgemm2(
    const ushort* __restrict__ Ab,
    const float* __restrict__ WlF, const float* __restrict__ WrF,
    ushort* __restrict__ qb, float* __restrict__ pbf, int N) {
    const int OC = 128;
    const int NT = OC / 16;
    const int LDW = 128 + 8;
    __shared__ ushort Wlds[OC * LDW];

    int tid = threadIdx.x;
    if (blockIdx.x == 0 && tid < 8) {       // zero sentinel row N of q2
        v8s z = {0, 0, 0, 0, 0, 0, 0, 0};
        *(v8s*)(qb + (size_t)N * 64 + tid * 8) = z;
    }
    // stage + cast W
    for (int it = 0; it < OC / 16; it++) {
        int idx = it * 256 + tid;
        int r = idx >> 4, kc = (idx & 15) * 8;
        const float* Wrow = (r < OC / 2) ? (WlF + (size_t)r * 128)
                                         : (WrF + (size_t)(r - OC / 2) * 128);
        float4 w0 = *(const float4*)(Wrow + kc);
        float4 w1 = *(const float4*)(Wrow + kc + 4);
        v8s wv;
        wv[0] = (short)f2b(w0.x); wv[1] = (short)f2b(w0.y);
        wv[2] = (short)f2b(w0.z); wv[3] = (short)f2b(w0.w);
        wv[4] = (short)f2b(w1.x); wv[5] = (short)f2b(w1.y);
        wv[6] = (short)f2b(w1.z); wv[7] = (short)f2b(w1.w);
        *(v8s*)((short*)Wlds + r * LDW + kc) = wv;
    }
    __syncthreads();

    int wave = tid >> 6;
    int lane = tid & 63;
    int m16 = lane & 15;
    int quad = lane >> 4;
    int rowbase = blockIdx.x * 128 + wave * 32;

    v4f acc[2][NT];
#pragma unroll
    for (int mt = 0; mt < 2; mt++)
#pragma unroll
        for (int t = 0; t < NT; t++) acc[mt][t] = {0.f, 0.f, 0.f, 0.f};

    int ar0 = min(rowbase + m16, N - 1);
    int ar1 = min(rowbase + 16 + m16, N - 1);

#pragma unroll
    for (int ks = 0; ks < 4; ks++) {
        int k0 = ks * 32 + quad * 8;
        v8s a0 = *(const v8s*)((const short*)Ab + (size_t)ar0 * 128 + k0);
        v8s a1 = *(const v8s*)((const short*)Ab + (size_t)ar1 * 128 + k0);
#pragma unroll
        for (int t = 0; t < NT; t++) {
            v8s b = *(const v8s*)((const short*)Wlds + (t * 16 + m16) * LDW + k0);
            acc[0][t] = __builtin_amdgcn_mfma_f32_16x16x32_bf16(a0, b, acc[0][t], 0, 0, 0);
            acc[1][t] = __builtin_amdgcn_mfma_f32_16x16x32_bf16(a1, b, acc[1][t], 0, 0, 0);
        }
    }

#pragma unroll
    for (int mt = 0; mt < 2; mt++) {
        int orow0 = rowbase + mt * 16 + quad * 4;
#pragma unroll
        for (int r = 0; r < 4; r++) {
            int orow = orow0 + r;
            if (orow < N) {
#pragma unroll
                for (int t = 0; t < NT; t++) {
                    int c = t * 16 + m16;
                    float v = acc[mt][t][r];
                    if (c < 64) qb[(size_t)orow * 64 + c] = f2b(v);
                    else pbf[(size_t)orow * 64 + (c - 64)] = v;
                }
            }
        }
    }
}

// ------------------- layer-1 aggregation: h = ReLU(mean(Q1) + P1 + b1) -> bf16
// r6-proven body + 32-bit row addressing (validated r9). Col loads
// UNCONDITIONAL (clamped index), select AFTER the load (r7 lesson).
__global__ __launch_bounds__(256, 8) void k_agg1(
    const int2* __restrict__ rowdeg,
    const int* __restrict__ col, const ushort* __restrict__ q1b,
    const ushort* __restrict__ p1b, const float* __restrict__ bias,
    ushort* __restrict__ hb, int N) {
    int node = blockIdx.x * (blockDim.x >> 6) + (threadIdx.x >> 6);
    int lane = threadIdx.x & 63;
    if (node >= N) return;
    int2 rd = rowdeg[node];
    int s0 = rd.x, dn = rd.y;
    int s1 = s0 + dn;
    int g = lane >> 4;                      // 4 groups of 16 lanes
    int ch = 8 * (lane & 15);               // 8 channels per lane, 16B loads
    // hoist epilogue row load: independent of gather, latency overlaps it
    v4u pb = *(const v4u*)((const ushort*)p1b + (size_t)node * 128 + ch);
    v4u pb2 = *(const v4u*)((const ushort*)p1b + (size_t)node * 128 + ch + 4);
    int last = (dn > 0) ? (s1 - 1) : s0;    // valid clamp target
    v2f a01 = {0.f, 0.f}, a23 = {0.f, 0.f}, a45 = {0.f, 0.f}, a67 = {0.f, 0.f};
    int j = s0;
    do {
        int i0 = j + g,      i1 = j + 4 + g,  i2 = j + 8 + g,  i3 = j + 12 + g;
        int i4 = j + 16 + g, i5 = j + 20 + g, i6 = j + 24 + g, i7 = j + 28 + g;
        int t0 = col[min(i0, last)];
        int t1 = col[min(i1, last)];
        int t2 = col[min(i2, last)];
        int t3 = col[min(i3, last)];
        int t4 = col[min(i4, last)];
        int t5 = col[min(i5, last)];
        int t6 = col[min(i6, last)];
        int t7 = col[min(i7, last)];
        int c0 = (i0 < s1) ? t0 : N;
        int c1 = (i1 < s1) ? t1 : N;
        int c2 = (i2 < s1) ? t2 : N;
        int c3 = (i3 < s1) ? t3 : N;
        int c4 = (i4 < s1) ? t4 : N;
        int c5 = (i5 < s1) ? t5 : N;
        int c6 = (i6 < s1) ? t6 : N;
        int c7 = (i7 < s1) ? t7 : N;
        uint4 r0 = *(const uint4*)(q1b + ((uint)c0 * 128u + (uint)ch));
        uint4 r1 = *(const uint4*)(q1b + ((uint)c1 * 128u + (uint)ch));
        uint4 r2 = *(const uint4*)(q1b + ((uint)c2 * 128u + (uint)ch));
        uint4 r3 = *(const uint4*)(q1b + ((uint)c3 * 128u + (uint)ch));
        uint4 r4 = *(const uint4*)(q1b + ((uint)c4 * 128u + (uint)ch));
        uint4 r5 = *(const uint4*)(q1b + ((uint)c5 * 128u + (uint)ch));
        uint4 r6 = *(const uint4*)(q1b + ((uint)c6 * 128u + (uint)ch));
        uint4 r7 = *(const uint4*)(q1b + ((uint)c7 * 128u + (uint)ch));
        ACC4(r0); ACC4(r1); ACC4(r2); ACC4(r3);
        ACC4(r4); ACC4(r5); ACC4(r6); ACC4(r7);
        j += 32;
    } while (j < s1);                       // deg>32: ~1e-4 of nodes
    float s[8] = {a01.x, a01.y, a23.x, a23.y, a45.x, a45.y, a67.x, a67.y};
#pragma unroll
    for (int k = 0; k < 8; k++) {
        s[k] += __shfl_xor(s[k], 16);
        s[k] += __shfl_xor(s[k], 32);
    }
    if (g == 0) {
        float inv = (dn > 0) ? 1.0f / (float)dn : 0.0f;
        float4 bi0 = *(const float4*)(bias + ch);
        float4 bi1 = *(const float4*)(bias + ch + 4);
        v8s o;
        o[0] = (short)f2b(fmaxf(s[0] * inv + b2f(pb.x) + bi0.x, 0.f));
        o[1] = (short)f2b(fmaxf(s[1] * inv + b2f(pb.y) + bi0.y, 0.f));
        o[2] = (short)f2b(fmaxf(s[2] * inv + b2f(pb.z) + bi0.z, 0.f));
        o[3] = (short)f2b(fmaxf(s[3] * inv + b2f(pb.w) + bi0.w, 0.f));
        o[4] = (short)f2b(fmaxf(s[4] * inv + b2f(pb2.x) + bi1.x, 0.f));
        o[5] = (short)f2b(fmaxf(s[5] * inv + b2f(pb2.y) + bi1.y, 0.f));
        o[6] = (short)f2b(fmaxf(s[6] * inv + b2f(pb2.z) + bi1.z, 0.f));
        o[7] = (short)f2b(fmaxf(s[7] * inv + b2f(pb2.w) + bi1.w, 0.f));
        *(v8s*)(hb + (size_t)node * 128 + ch) = o;
    }
}

// ------------------- layer-2 aggregation: out = mean(Q2) + P2 + b2 -> fp32
// r6-proven body + 32-bit row addressing (validated r9).
__global__ __launch_bounds__(256, 8) void k_agg2(
    const int2* __restrict__ rowdeg,
    const int* __restrict__ col, const ushort* __restrict__ q2,
    const float* __restrict__ p2, const float* __restrict__ bias,
    float* __restrict__ out, int N) {
    int node = blockIdx.x * (blockDim.x >> 6) + (threadIdx.x >> 6);
    int lane = threadIdx.x & 63;
    if (node >= N) return;
    int2 rd = rowdeg[node];
    int s0 = rd.x, dn = rd.y;
    int s1 = s0 + dn;
    int g = lane >> 3;                      // 8 groups of 8 lanes
    int ch = 8 * (lane & 7);                // 8 channels per lane, 16B loads
    // hoist epilogue loads (independent of gather)
    v4f p0 = *(const v4f*)(p2 + (size_t)node * 64 + ch);
    v4f p1 = *(const v4f*)(p2 + (size_t)node * 64 + ch + 4);
    int last = (dn > 0) ? (s1 - 1) : s0;
    v2f a01 = {0.f, 0.f}, a23 = {0.f, 0.f}, a45 = {0.f, 0.f}, a67 = {0.f, 0.f};
    int j = s0;
    do {
        int i0 = j + g, i1 = j + 8 + g, i2 = j + 16 + g, i3 = j + 24 + g;
        int t0 = col[min(i0, last)];
        int t1 = col[min(i1, last)];
        int t2 = col[min(i2, last)];
        int t3 = col[min(i3, last)];
        int c0 = (i0 < s1) ? t0 : N;
        int c1 = (i1 < s1) ? t1 : N;
        int c2 = (i2 < s1) ? t2 : N;
        int c3 = (i3 < s1) ? t3 : N;
        uint4 r0 = *(const uint4*)(q2 + ((uint)c0 * 64u + (uint)ch));
        uint4 r1 = *(const uint4*)(q2 + ((uint)c1 * 64u + (uint)ch));
        uint4 r2 = *(const uint4*)(q2 + ((uint)c2 * 64u + (uint)ch));
        uint4 r3 = *(const uint4*)(q2 + ((uint)c3 * 64u + (uint)ch));
        ACC4(r0); ACC4(r1); ACC4(r2); ACC4(r3);
        j += 32;
    } while (j < s1);
    float s[8] = {a01.x, a01.y, a23.x, a23.y, a45.x, a45.y, a67.x, a67.y};
#pragma unroll
    for (int k = 0; k < 8; k++) {
        s[k] += __shfl_xor(s[k], 8);
        s[k] += __shfl_xor(s[k], 16);
        s[k] += __shfl_xor(s[k], 32);
    }
    if (g == 0) {
        float inv = (dn > 0) ? 1.0f / (float)dn : 0.0f;
        float4 bi0 = *(const float4*)(bias + ch);
        float4 bi1 = *(const float4*)(bias + ch + 4);
        v4f o0, o1;
        o0[0] = s[0] * inv + p0[0] + bi0.x;
        o0[1] = s[1] * inv + p0[1] + bi0.y;
        o0[2] = s[2] * inv + p0[2] + bi0.z;
        o0[3] = s[3] * inv + p0[3] + bi0.w;
        o1[0] = s[4] * inv + p1[0] + bi1.x;
        o1[1] = s[5] * inv + p1[1] + bi1.y;
        o1[2] = s[6] * inv + p1[2] + bi1.z;
        o1[3] = s[7] * inv + p1[3] + bi1.w;
        *(v4f*)(out + (size_t)node * 64 + ch) = o0;
        *(v4f*)(out + (size_t)node * 64 + ch + 4) = o1;
    }
}

extern "C" void kernel_launch(void* const* d_in, const int* in_sizes, int n_in,
                              void* d_out, int out_size, void* d_ws, size_t ws_size,
                              hipStream_t stream) {
    const float* x   = (const float*)d_in[0];
    const int* ei    = (const int*)d_in[1];
    const float* Wl1 = (const float*)d_in[2];
    const float* bl1 = (const float*)d_in[3];
    const float* Wr1 = (const float*)d_in[4];
    const float* Wl2 = (const float*)d_in[5];
    const float* bl2 = (const float*)d_in[6];
    const float* Wr2 = (const float*)d_in[7];

    const int N = in_sizes[0] / IN_CH;   // 100000
    const int E = in_sizes[1] / 2;       // 1600000
    const int* src = ei;
    const int* dst = ei + E;

    char* p = (char*)d_ws;
    auto carve = [&](size_t bytes) -> void* {
        void* q = (void*)p;
        p += (bytes + 255) & ~(size_t)255;
        return q;
    };
    int* cursor   = (int*)carve(NBUCK * 4);
    int* ebuf     = (int*)carve((size_t)NBUCK * CAP * 4);
    int* col      = (int*)carve((size_t)NBUCK * CAP * 4 + 256);
    int2* rowdeg  = (int2*)carve((size_t)N * 8);
    ushort* q1b   = (ushort*)carve(((size_t)N + 1) * 128 * 2);  // +1 zero row
    ushort* p1b   = (ushort*)carve((size_t)N * 128 * 2);
    ushort* hb    = (ushort*)carve((size_t)N * 128 * 2);
    ushort* q2    = (ushort*)carve(((size_t)N + 1) * 64 * 2);   // +1 zero row
    float* p2     = (float*)carve((size_t)N * 64 * 4);
    (void)ws_size; (void)n_in;

    float* out = (float*)d_out;
    (void)out_size;

    const int PB = (E + PART_EPB - 1) / PART_EPB;    // 782 partition blocks
    const int GB = (N + 127) / 128;                  // 782 gemm blocks

    // ---- partition; then fused {CSR build + layer-1 GEMM} (independent) ----
    (void)hipMemsetAsync(cursor, 0, NBUCK * 4, stream);
    k_part<<<PB, 256, 0, stream>>>(src, dst, cursor, ebuf, E);
    k_bbuild_gemm1<<<NBUCK + GB, 256, 0, stream>>>(
        ebuf, cursor, rowdeg, col, x, Wl1, Wr1, q1b, p1b, N);

    // ---- h = ReLU(mean(Q1)+P1+b1) ----
    k_agg1<<<(N + 3) / 4, 256, 0, stream>>>(rowdeg, col, q1b, p1b, bl1, hb, N);

    // ---- layer 2: [Q2|P2] = hb @ [Wl2;Wr2].T; out = mean(Q2)+P2+b2 ----
    k_wgemm2<<<GB, 256, 0, stream>>>(hb, Wl2, Wr2, q2, p2, N);
    k_agg2<<<(N + 3) / 4, 256, 0, stream>>>(rowdeg, col, q2, p2, bl2, out, N);
}

// Round 11
// 278.612 us; speedup vs baseline: 1.0205x; 1.0023x over previous
//
#include <hip/hip_runtime.h>
#include <hip/hip_bf16.h>
#include <stdint.h>

#define IN_CH 128
#define NPB   448            // nodes per bucket
#define NBUCK 224            // NBUCK*NPB = 100352 >= N
#define CAP   8192           // edge capacity per bucket region (avg ~7150)
#define PART_EPB 2048        // edges per partition block (782 blocks)
#define SRC_BITS 17          // src < 131072
#define SRC_MASK ((1 << SRC_BITS) - 1)

typedef short v8s __attribute__((ext_vector_type(8)));
typedef float v4f __attribute__((ext_vector_type(4)));
typedef float v2f __attribute__((ext_vector_type(2)));
typedef ushort v4u __attribute__((ext_vector_type(4)));

__device__ __forceinline__ ushort f2b(float f) {
    return ((__hip_bfloat16_raw)__float2bfloat16(f)).x;
}
__device__ __forceinline__ float b2f(ushort u) {
    __hip_bfloat16_raw r; r.x = u;
    return __bfloat162float((__hip_bfloat16)r);
}

// uint4 of 8 packed bf16 -> four packed f32 pair-adds (v_pk_add_f32)
#define ACC4(r) {                                                            \
    a01 += (v2f){__uint_as_float((r).x << 16),                               \
                 __uint_as_float((r).x & 0xffff0000u)};                      \
    a23 += (v2f){__uint_as_float((r).y << 16),                               \
                 __uint_as_float((r).y & 0xffff0000u)};                      \
    a45 += (v2f){__uint_as_float((r).z << 16),                               \
                 __uint_as_float((r).z & 0xffff0000u)};                      \
    a67 += (v2f){__uint_as_float((r).w << 16),                               \
                 __uint_as_float((r).w & 0xffff0000u)}; }

// ---------------------------------- coalesced radix partition of edges by dst
// STANDALONE (r9 lesson: fusing with the 69.6KB-LDS gemm role cut occupancy
// and serialized it). dst staged in LDS (no 2nd global read pass); per-edge
// bucket id in sbuck[] (int, not byte: byte scatter = bank-word conflicts).
__global__ __launch_bounds__(256) void k_part(
    const int* __restrict__ src, const int* __restrict__ dst,
    int* __restrict__ cursor, int* __restrict__ ebuf, int E) {
    __shared__ int sedge[PART_EPB];                    // 8 KB
    __shared__ int sdst[PART_EPB];                     // 8 KB
    __shared__ int sbuck[PART_EPB];                    // 8 KB
    __shared__ int h[NBUCK], lofs[NBUCK], gbase[NBUCK], lcur[NBUCK];
    __shared__ int ssc[256];

    int tid = threadIdx.x;
    int eb0 = blockIdx.x * PART_EPB;
    int cnt = min(PART_EPB, E - eb0);

    if (tid < NBUCK) { h[tid] = 0; lcur[tid] = 0; }
    __syncthreads();
    for (int i = tid; i < cnt; i += 256) {
        int d = dst[eb0 + i];
        sdst[i] = d;
        atomicAdd(&h[d / NPB], 1);
    }
    __syncthreads();
    int v = (tid < NBUCK) ? h[tid] : 0;
    ssc[tid] = v;
    __syncthreads();
    for (int off = 1; off < 256; off <<= 1) {
        int val = (tid >= off) ? ssc[tid - off] : 0;
        __syncthreads();
        ssc[tid] += val;
        __syncthreads();
    }
    int excl = ssc[tid] - v;
    if (tid < NBUCK) {
        lofs[tid] = excl;
        gbase[tid] = tid * CAP + atomicAdd(&cursor[tid], v);
    }
    __syncthreads();
    for (int i = tid; i < cnt; i += 256) {
        int s0 = src[eb0 + i];
        int d0 = sdst[i];
        int b = d0 / NPB;
        int dl = d0 - b * NPB;
        int p = atomicAdd(&lcur[b], 1);
        int slot = lofs[b] + p;
        sedge[slot] = (dl << SRC_BITS) | s0;
        sbuck[slot] = b;
    }
    __syncthreads();
    for (int i = tid; i < cnt; i += 256) {
        int b = sbuck[i];
        int pos = gbase[b] + (i - lofs[b]);
        if (pos < (b + 1) * CAP) ebuf[pos] = sedge[i];  // overflow guard
    }
}

// ------------- FUSED: per-bucket CSR build (blocks 0..NBUCK-1)  +
//               layer-1 GEMM [Q1|P1] = x @ [Wl1;Wr1].T (blocks NBUCK..)
// r8-proven pairing: bbuild is small so the gemm path's 69.6KB LDS costs it
// nothing; roles independent. First gemm block zeroes the q1b sentinel row.
__global__ __launch_bounds__(256) void k_bbuild_gemm1(
    const int* __restrict__ ebuf, const int* __restrict__ cursor,
    int2* __restrict__ rowdeg, int* __restrict__ col,
    const float* __restrict__ Af,
    const float* __restrict__ WlF, const float* __restrict__ WrF,
    ushort* __restrict__ qb, ushort* __restrict__ pbb, int N) {
    const int OC = 256;
    const int NT = OC / 16;
    const int LDW = 128 + 8;
    __shared__ ushort Wlds[OC * LDW];                  // 69.6 KB (gemm role)
    __shared__ int sdeg[NPB];                          // bbuild role
    __shared__ int scur[NPB];
    __shared__ int ssum[256];

    int tid = threadIdx.x;

    if (blockIdx.x < NBUCK) {
        // ---------------- bbuild role ----------------
        int b = blockIdx.x;
        int base = b * NPB;
        int nodes = min(NPB, N - base);
        int e0 = b * CAP;
        int e1 = e0 + min(cursor[b], CAP);

        for (int i = tid; i < NPB; i += 256) sdeg[i] = 0;
        __syncthreads();
        for (int e = e0 + tid; e < e1; e += 256)
            atomicAdd(&sdeg[((unsigned)ebuf[e]) >> SRC_BITS], 1);
        __syncthreads();
        int d0 = 0, d1 = 0;
        if (tid < 224) { d0 = sdeg[2 * tid]; d1 = sdeg[2 * tid + 1]; }
        int ts = d0 + d1;
        ssum[tid] = ts;
        __syncthreads();
        for (int off = 1; off < 256; off <<= 1) {
            int val = (tid >= off) ? ssum[tid - off] : 0;
            __syncthreads();
            ssum[tid] += val;
            __syncthreads();
        }
        int excl = ssum[tid] - ts;
        if (tid < 224) {
            scur[2 * tid] = excl;
            scur[2 * tid + 1] = excl + d0;
            if (2 * tid < nodes)
                rowdeg[base + 2 * tid] = make_int2(e0 + excl, d0);
            if (2 * tid + 1 < nodes)
                rowdeg[base + 2 * tid + 1] = make_int2(e0 + excl + d0, d1);
        }
        __syncthreads();
        for (int e = e0 + tid; e < e1; e += 256) {
            int w = ebuf[e];
            int dl = ((unsigned)w) >> SRC_BITS;
            int p = atomicAdd(&scur[dl], 1);
            col[e0 + p] = w & SRC_MASK;
        }
        return;
    }

    // ---------------- gemm role ----------------
    int gb = blockIdx.x - NBUCK;
    if (gb == 0 && tid < 16) {              // zero sentinel row N of q1b
        v8s z = {0, 0, 0, 0, 0, 0, 0, 0};
        *(v8s*)(qb + (size_t)N * 128 + tid * 8) = z;
    }

    // stage + cast W: OC rows x 128 k, 8 floats per thread-chunk
    for (int it = 0; it < OC / 16; it++) {
        int idx = it * 256 + tid;
        int r = idx >> 4, kc = (idx & 15) * 8;
        const float* Wrow = (r < OC / 2) ? (WlF + (size_t)r * 128)
                                         : (WrF + (size_t)(r - OC / 2) * 128);
        float4 w0 = *(const float4*)(Wrow + kc);
        float4 w1 = *(const float4*)(Wrow + kc + 4);
        v8s wv;
        wv[0] = (short)f2b(w0.x); wv[1] = (short)f2b(w0.y);
        wv[2] = (short)f2b(w0.z); wv[3] = (short)f2b(w0.w);
        wv[4] = (short)f2b(w1.x); wv[5] = (short)f2b(w1.y);
        wv[6] = (short)f2b(w1.z); wv[7] = (short)f2b(w1.w);
        *(v8s*)((short*)Wlds + r * LDW + kc) = wv;
    }
    __syncthreads();

    int wave = tid >> 6;
    int lane = tid & 63;
    int m16 = lane & 15;
    int quad = lane >> 4;
    int rowbase = gb * 128 + wave * 32;

    v4f acc[2][NT];
#pragma unroll
    for (int mt = 0; mt < 2; mt++)
#pragma unroll
        for (int t = 0; t < NT; t++) acc[mt][t] = {0.f, 0.f, 0.f, 0.f};

    int ar0 = min(rowbase + m16, N - 1);
    int ar1 = min(rowbase + 16 + m16, N - 1);

#pragma unroll
    for (int ks = 0; ks < 4; ks++) {
        int k0 = ks * 32 + quad * 8;
        float4 f00 = *(const float4*)(Af + (size_t)ar0 * 128 + k0);
        float4 f01 = *(const float4*)(Af + (size_t)ar0 * 128 + k0 + 4);
        float4 f10 = *(const float4*)(Af + (size_t)ar1 * 128 + k0);
        float4 f11 = *(const float4*)(Af + (size_t)ar1 * 128 + k0 + 4);
        v8s a0, a1;
        a0[0] = (short)f2b(f00.x); a0[1] = (short)f2b(f00.y);
        a0[2] = (short)f2b(f00.z); a0[3] = (short)f2b(f00.w);
        a0[4] = (short)f2b(f01.x); a0[5] = (short)f2b(f01.y);
        a0[6] = (short)f2b(f01.z); a0[7] = (short)f2b(f01.w);
        a1[0] = (short)f2b(f10.x); a1[1] = (short)f2b(f10.y);
        a1[2] = (short)f2b(f10.z); a1[3] = (short)f2b(f10.w);
        a1[4] = (short)f2b(f11.x); a1[5] = (short)f2b(f11.y);
        a1[6] = (short)f2b(f11.z); a1[7] = (short)f2b(f11.w);
#pragma unroll
        for (int t = 0; t < NT; t++) {
            v8s b = *(const v8s*)((const short*)Wlds + (t * 16 + m16) * LDW + k0);
            acc[0][t] = __builtin_amdgcn_mfma_f32_16x16x32_bf16(a0, b, acc[0][t], 0, 0, 0);
            acc[1][t] = __builtin_amdgcn_mfma_f32_16x16x32_bf16(a1, b, acc[1][t], 0, 0, 0);
        }
    }

    // C/D layout: col = t*16 + m16, row(within tile) = quad*4 + r
#pragma unroll
    for (int mt = 0; mt < 2; mt++) {
        int orow0 = rowbase + mt * 16 + quad * 4;
#pragma unroll
        for (int r = 0; r < 4; r++) {
            int orow = orow0 + r;
            if (orow < N) {
#pragma unroll
                for (int t = 0; t < NT; t++) {
                    int c = t * 16 + m16;
                    float v = acc[mt][t][r];
                    if (c < 128) qb[(size_t)orow * 128 + c] = f2b(v);
                    else pbb[(size_t)orow * 128 + (c - 128)] = f2b(v);
                }
            }
        }
    }
}

// ------------------------------------------------- layer-2 GEMM, W in LDS
// A = hb bf16 [N][128], OC=128: c<64 -> q2[N][64] bf16, c>=64 -> p2[N][64] f32
// First block zeroes the q2 sentinel row (replaces a memset dispatch).
__global__ __launch_bounds__(256) void k_wgemm2(
    const ushort* __restrict__ Ab,
    const float* __restrict__ WlF, const float* __restrict__ WrF,
    ushort* __restrict__ qb, float* __restrict__ pbf, int N) {
    const int OC = 128;
    const int NT = OC / 16;
    const int LDW = 128 + 8;
    __shared__ ushort Wlds[OC * LDW];

    int tid = threadIdx.x;
    if (blockIdx.x == 0 && tid < 8) {       // zero sentinel row N of q2
        v8s z = {0, 0, 0, 0, 0, 0, 0, 0};
        *(v8s*)(qb + (size_t)N * 64 + tid * 8) = z;
    }
    // stage + cast W
    for (int it = 0; it < OC / 16; it++) {
        int idx = it * 256 + tid;
        int r = idx >> 4, kc = (idx & 15) * 8;
        const float* Wrow = (r < OC / 2) ? (WlF + (size_t)r * 128)
                                         : (WrF + (size_t)(r - OC / 2) * 128);
        float4 w0 = *(const float4*)(Wrow + kc);
        float4 w1 = *(const float4*)(Wrow + kc + 4);
        v8s wv;
        wv[0] = (short)f2b(w0.x); wv[1] = (short)f2b(w0.y);
        wv[2] = (short)f2b(w0.z); wv[3] = (short)f2b(w0.w);
        wv[4] = (short)f2b(w1.x); wv[5] = (short)f2b(w1.y);
        wv[6] = (short)f2b(w1.z); wv[7] = (short)f2b(w1.w);
        *(v8s*)((short*)Wlds + r * LDW + kc) = wv;
    }
    __syncthreads();

    int wave = tid >> 6;
    int lane = tid & 63;
    int m16 = lane & 15;
    int quad = lane >> 4;
    int rowbase = blockIdx.x * 128 + wave * 32;

    v4f acc[2][NT];
#pragma unroll
    for (int mt = 0; mt < 2; mt++)
#pragma unroll
        for (int t = 0; t < NT; t++) acc[mt][t] = {0.f, 0.f, 0.f, 0.f};

    int ar0 = min(rowbase + m16, N - 1);
    int ar1 = min(rowbase + 16 + m16, N - 1);

#pragma unroll
    for (int ks = 0; ks < 4; ks++) {
        int k0 = ks * 32 + quad * 8;
        v8s a0 = *(const v8s*)((const short*)Ab + (size_t)ar0 * 128 + k0);
        v8s a1 = *(const v8s*)((const short*)Ab + (size_t)ar1 * 128 + k0);
#pragma unroll
        for (int t = 0; t < NT; t++) {
            v8s b = *(const v8s*)((const short*)Wlds + (t * 16 + m16) * LDW + k0);
            acc[0][t] = __builtin_amdgcn_mfma_f32_16x16x32_bf16(a0, b, acc[0][t], 0, 0, 0);
            acc[1][t] = __builtin_amdgcn_mfma_f32_16x16x32_bf16(a1, b, acc[1][t], 0, 0, 0);
        }
    }

#pragma unroll
    for (int mt = 0; mt < 2; mt++) {
        int orow0 = rowbase + mt * 16 + quad * 4;
#pragma unroll
        for (int r = 0; r < 4; r++) {
            int orow = orow0 + r;
            if (orow < N) {
#pragma unroll
                for (int t = 0; t < NT; t++) {
                    int c = t * 16 + m16;
                    float v = acc[mt][t][r];
                    if (c < 64) qb[(size_t)orow * 64 + c] = f2b(v);
                    else pbf[(size_t)orow * 64 + (c - 64)] = v;
                }
            }
        }
    }
}

// ------------------- layer-1 aggregation: h = ReLU(mean(Q1) + P1 + b1) -> bf16
// r10-proven body + WAVE-UNIFORM DEGREE TIERS (retry of r7's idea with the
// proven load discipline: col loads UNCONDITIONAL clamped, select AFTER the
// load — r7's regression was load-inside-select, not tiering):
//   deg <= 16 (47%): single 4-slot block (16 rows in flight, no sentinel
//                    dupes: -4 loads, -48 unpack VALU, -12 addr VALU)
//   deg >  16: exact r10 8-slot do-while (32 edges/iter).
__global__ __launch_bounds__(256, 8) void k_agg1(
    const int2* __restrict__ rowdeg,
    const int* __restrict__ col, const ushort* __restrict__ q1b,
    const ushort* __restrict__ p1b, const float* __restrict__ bias,
    ushort* __restrict__ hb, int N) {
    int node = blockIdx.x * (blockDim.x >> 6) + (threadIdx.x >> 6);
    int lane = threadIdx.x & 63;
    if (node >= N) return;
    int2 rd = rowdeg[node];
    int s0 = rd.x, dn = rd.y;
    int s1 = s0 + dn;
    int g = lane >> 4;                      // 4 groups of 16 lanes
    int ch = 8 * (lane & 15);               // 8 channels per lane, 16B loads
    // hoist epilogue row load: independent of gather, latency overlaps it
    v4u pb = *(const v4u*)((const ushort*)p1b + (size_t)node * 128 + ch);
    v4u pb2 = *(const v4u*)((const ushort*)p1b + (size_t)node * 128 + ch + 4);
    int last = (dn > 0) ? (s1 - 1) : s0;    // valid clamp target
    v2f a01 = {0.f, 0.f}, a23 = {0.f, 0.f}, a45 = {0.f, 0.f}, a67 = {0.f, 0.f};
    if (dn <= 16) {                         // tier 1: one 4-slot epoch
        int i0 = s0 + g, i1 = s0 + 4 + g, i2 = s0 + 8 + g, i3 = s0 + 12 + g;
        int t0 = col[min(i0, last)];
        int t1 = col[min(i1, last)];
        int t2 = col[min(i2, last)];
        int t3 = col[min(i3, last)];
        int c0 = (i0 < s1) ? t0 : N;
        int c1 = (i1 < s1) ? t1 : N;
        int c2 = (i2 < s1) ? t2 : N;
        int c3 = (i3 < s1) ? t3 : N;
        uint4 r0 = *(const uint4*)(q1b + ((uint)c0 * 128u + (uint)ch));
        uint4 r1 = *(const uint4*)(q1b + ((uint)c1 * 128u + (uint)ch));
        uint4 r2 = *(const uint4*)(q1b + ((uint)c2 * 128u + (uint)ch));
        uint4 r3 = *(const uint4*)(q1b + ((uint)c3 * 128u + (uint)ch));
        ACC4(r0); ACC4(r1); ACC4(r2); ACC4(r3);
    } else {                                // tier 2: 32-edge blocks (r10)
        int j = s0;
        do {
            int i0 = j + g,      i1 = j + 4 + g,  i2 = j + 8 + g,  i3 = j + 12 + g;
            int i4 = j + 16 + g, i5 = j + 20 + g, i6 = j + 24 + g, i7 = j + 28 + g;
            int t0 = col[min(i0, last)];
            int t1 = col[min(i1, last)];
            int t2 = col[min(i2, last)];
            int t3 = col[min(i3, last)];
            int t4 = col[min(i4, last)];
            int t5 = col[min(i5, last)];
            int t6 = col[min(i6, last)];
            int t7 = col[min(i7, last)];
            int c0 = (i0 < s1) ? t0 : N;
            int c1 = (i1 < s1) ? t1 : N;
            int c2 = (i2 < s1) ? t2 : N;
            int c3 = (i3 < s1) ? t3 : N;
            int c4 = (i4 < s1) ? t4 : N;
            int c5 = (i5 < s1) ? t5 : N;
            int c6 = (i6 < s1) ? t6 : N;
            int c7 = (i7 < s1) ? t7 : N;
            uint4 r0 = *(const uint4*)(q1b + ((uint)c0 * 128u + (uint)ch));
            uint4 r1 = *(const uint4*)(q1b + ((uint)c1 * 128u + (uint)ch));
            uint4 r2 = *(const uint4*)(q1b + ((uint)c2 * 128u + (uint)ch));
            uint4 r3 = *(const uint4*)(q1b + ((uint)c3 * 128u + (uint)ch));
            uint4 r4 = *(const uint4*)(q1b + ((uint)c4 * 128u + (uint)ch));
            uint4 r5 = *(const uint4*)(q1b + ((uint)c5 * 128u + (uint)ch));
            uint4 r6 = *(const uint4*)(q1b + ((uint)c6 * 128u + (uint)ch));
            uint4 r7 = *(const uint4*)(q1b + ((uint)c7 * 128u + (uint)ch));
            ACC4(r0); ACC4(r1); ACC4(r2); ACC4(r3);
            ACC4(r4); ACC4(r5); ACC4(r6); ACC4(r7);
            j += 32;
        } while (j < s1);                   // deg>32: ~1e-4 of nodes
    }
    float s[8] = {a01.x, a01.y, a23.x, a23.y, a45.x, a45.y, a67.x, a67.y};
#pragma unroll
    for (int k = 0; k < 8; k++) {
        s[k] += __shfl_xor(s[k], 16);
        s[k] += __shfl_xor(s[k], 32);
    }
    if (g == 0) {
        float inv = (dn > 0) ? 1.0f / (float)dn : 0.0f;
        float4 bi0 = *(const float4*)(bias + ch);
        float4 bi1 = *(const float4*)(bias + ch + 4);
        v8s o;
        o[0] = (short)f2b(fmaxf(s[0] * inv + b2f(pb.x) + bi0.x, 0.f));
        o[1] = (short)f2b(fmaxf(s[1] * inv + b2f(pb.y) + bi0.y, 0.f));
        o[2] = (short)f2b(fmaxf(s[2] * inv + b2f(pb.z) + bi0.z, 0.f));
        o[3] = (short)f2b(fmaxf(s[3] * inv + b2f(pb.w) + bi0.w, 0.f));
        o[4] = (short)f2b(fmaxf(s[4] * inv + b2f(pb2.x) + bi1.x, 0.f));
        o[5] = (short)f2b(fmaxf(s[5] * inv + b2f(pb2.y) + bi1.y, 0.f));
        o[6] = (short)f2b(fmaxf(s[6] * inv + b2f(pb2.z) + bi1.z, 0.f));
        o[7] = (short)f2b(fmaxf(s[7] * inv + b2f(pb2.w) + bi1.w, 0.f));
        *(v8s*)(hb + (size_t)node * 128 + ch) = o;
    }
}

// ------------------- layer-2 aggregation: out = mean(Q2) + P2 + b2 -> fp32
// r10-proven body + same degree tiers: deg<=16 -> 2-slot block; else 4-slot
// do-while. Col loads unconditional-clamped, select after.
__global__ __launch_bounds__(256, 8) void k_agg2(
    const int2* __restrict__ rowdeg,
    const int* __restrict__ col, const ushort* __restrict__ q2,
    const float* __restrict__ p2, const float* __restrict__ bias,
    float* __restrict__ out, int N) {
    int node = blockIdx.x * (blockDim.x >> 6) + (threadIdx.x >> 6);
    int lane = threadIdx.x & 63;
    if (node >= N) return;
    int2 rd = rowdeg[node];
    int s0 = rd.x, dn = rd.y;
    int s1 = s0 + dn;
    int g = lane >> 3;                      // 8 groups of 8 lanes
    int ch = 8 * (lane & 7);                // 8 channels per lane, 16B loads
    // hoist epilogue loads (independent of gather)
    v4f p0 = *(const v4f*)(p2 + (size_t)node * 64 + ch);
    v4f p1 = *(const v4f*)(p2 + (size_t)node * 64 + ch + 4);
    int last = (dn > 0) ? (s1 - 1) : s0;
    v2f a01 = {0.f, 0.f}, a23 = {0.f, 0.f}, a45 = {0.f, 0.f}, a67 = {0.f, 0.f};
    if (dn <= 16) {                         // tier 1: one 2-slot epoch
        int i0 = s0 + g, i1 = s0 + 8 + g;
        int t0 = col[min(i0, last)];
        int t1 = col[min(i1, last)];
        int c0 = (i0 < s1) ? t0 : N;
        int c1 = (i1 < s1) ? t1 : N;
        uint4 r0 = *(const uint4*)(q2 + ((uint)c0 * 64u + (uint)ch));
        uint4 r1 = *(const uint4*)(q2 + ((uint)c1 * 64u + (uint)ch));
        ACC4(r0); ACC4(r1);
    } else {                                // tier 2: 32-edge blocks (r10)
        int j = s0;
        do {
            int i0 = j + g, i1 = j + 8 + g, i2 = j + 16 + g, i3 = j + 24 + g;
            int t0 = col[min(i0, last)];
            int t1 = col[min(i1, last)];
            int t2 = col[min(i2, last)];
            int t3 = col[min(i3, last)];
            int c0 = (i0 < s1) ? t0 : N;
            int c1 = (i1 < s1) ? t1 : N;
            int c2 = (i2 < s1) ? t2 : N;
            int c3 = (i3 < s1) ? t3 : N;
            uint4 r0 = *(const uint4*)(q2 + ((uint)c0 * 64u + (uint)ch));
            uint4 r1 = *(const uint4*)(q2 + ((uint)c1 * 64u + (uint)ch));
            uint4 r2 = *(const uint4*)(q2 + ((uint)c2 * 64u + (uint)ch));
            uint4 r3 = *(const uint4*)(q2 + ((uint)c3 * 64u + (uint)ch));
            ACC4(r0); ACC4(r1); ACC4(r2); ACC4(r3);
            j += 32;
        } while (j < s1);
    }
    float s[8] = {a01.x, a01.y, a23.x, a23.y, a45.x, a45.y, a67.x, a67.y};
#pragma unroll
    for (int k = 0; k < 8; k++) {
        s[k] += __shfl_xor(s[k], 8);
        s[k] += __shfl_xor(s[k], 16);
        s[k] += __shfl_xor(s[k], 32);
    }
    if (g == 0) {
        float inv = (dn > 0) ? 1.0f / (float)dn : 0.0f;
        float4 bi0 = *(const float4*)(bias + ch);
        float4 bi1 = *(const float4*)(bias + ch + 4);
        v4f o0, o1;
        o0[0] = s[0] * inv + p0[0] + bi0.x;
        o0[1] = s[1] * inv + p0[1] + bi0.y;
        o0[2] = s[2] * inv + p0[2] + bi0.z;
        o0[3] = s[3] * inv + p0[3] + bi0.w;
        o1[0] = s[4] * inv + p1[0] + bi1.x;
        o1[1] = s[5] * inv + p1[1] + bi1.y;
        o1[2] = s[6] * inv + p1[2] + bi1.z;
        o1[3] = s[7] * inv + p1[3] + bi1.w;
        *(v4f*)(out + (size_t)node * 64 + ch) = o0;
        *(v4f*)(out + (size_t)node * 64 + ch + 4) = o1;
    }
}

extern "C" void kernel_launch(void* const* d_in, const int* in_sizes, int n_in,
                              void* d_out, int out_size, void* d_ws, size_t ws_size,
                              hipStream_t stream) {
    const float* x   = (const float*)d_in[0];
    const int* ei    = (const int*)d_in[1];
    const float* Wl1 = (const float*)d_in[2];
    const float* bl1 = (const float*)d_in[3];
    const float* Wr1 = (const float*)d_in[4];
    const float* Wl2 = (const float*)d_in[5];
    const float* bl2 = (const float*)d_in[6];
    const float* Wr2 = (const float*)d_in[7];

    const int N = in_sizes[0] / IN_CH;   // 100000
    const int E = in_sizes[1] / 2;       // 1600000
    const int* src = ei;
    const int* dst = ei + E;

    char* p = (char*)d_ws;
    auto carve = [&](size_t bytes) -> void* {
        void* q = (void*)p;
        p += (bytes + 255) & ~(size_t)255;
        return q;
    };
    int* cursor   = (int*)carve(NBUCK * 4);
    int* ebuf     = (int*)carve((size_t)NBUCK * CAP * 4);
    int* col      = (int*)carve((size_t)NBUCK * CAP * 4 + 256);
    int2* rowdeg  = (int2*)carve((size_t)N * 8);
    ushort* q1b   = (ushort*)carve(((size_t)N + 1) * 128 * 2);  // +1 zero row
    ushort* p1b   = (ushort*)carve((size_t)N * 128 * 2);
    ushort* hb    = (ushort*)carve((size_t)N * 128 * 2);
    ushort* q2    = (ushort*)carve(((size_t)N + 1) * 64 * 2);   // +1 zero row
    float* p2     = (float*)carve((size_t)N * 64 * 4);
    (void)ws_size; (void)n_in;

    float* out = (float*)d_out;
    (void)out_size;

    const int PB = (E + PART_EPB - 1) / PART_EPB;    // 782 partition blocks
    const int GB = (N + 127) / 128;                  // 782 gemm blocks

    // ---- partition; then fused {CSR build + layer-1 GEMM} (independent) ----
    (void)hipMemsetAsync(cursor, 0, NBUCK * 4, stream);
    k_part<<<PB, 256, 0, stream>>>(src, dst, cursor, ebuf, E);
    k_bbuild_gemm1<<<NBUCK + GB, 256, 0, stream>>>(
        ebuf, cursor, rowdeg, col, x, Wl1, Wr1, q1b, p1b, N);

    // ---- h = ReLU(mean(Q1)+P1+b1) ----
    k_agg1<<<(N + 3) / 4, 256, 0, stream>>>(rowdeg, col, q1b, p1b, bl1, hb, N);

    // ---- layer 2: [Q2|P2] = hb @ [Wl2;Wr2].T; out = mean(Q2)+P2+b2 ----
    k_wgemm2<<<GB, 256, 0, stream>>>(hb, Wl2, Wr2, q2, p2, N);
    k_agg2<<<(N + 3) / 4, 256, 0, stream>>>(rowdeg, col, q2, p2, bl2, out, N);
}